// Round 10
// baseline (429.471 us; speedup 1.0000x reference)
//
#include <hip/hip_runtime.h>
#include <hip/hip_cooperative_groups.h>

namespace cg = cooperative_groups;

#define DD 64
#define NEG_SLOPE 0.2f
#define HS 68          // padded LDS stride for h tile
#define CAP 64         // per-node register path capacity (deg~Pois(16))
#define BSH 8          // bucket = dst >> 8 (256 nodes per bucket)
#define BN  256        // nodes per bucket
#define NBMAX 256      // max buckets supported by LDS hists
#define NBLK 256       // edge-chunk blocks for the multi-split
#define CAPB 6144      // per-bucket region capacity (mean ~4082, >30 sigma)
#define STAGE_CAP 6144 // LDS col staging per bucket (== CAPB: always fits)
#define AMM_NODES 32   // nodes per aggregation tile (8 waves x 4 groups)
#define CWS 65         // cw row stride (uint2) — padded to break bank conflicts
#define SMEM_BYTES 34816  // union: mm 33.8K / gb 27.1K / agg 33.0K

// fp32 -> bf16 with round-to-nearest-even (finite inputs)
__device__ __forceinline__ unsigned short f2bf(float f)
{
    unsigned u = __float_as_uint(f);
    u += 0x7FFFu + ((u >> 16) & 1u);
    return (unsigned short)(u >> 16);
}
__device__ __forceinline__ float bf2f(unsigned short b)
{
    return __uint_as_float(((unsigned)b) << 16);
}

__device__ __forceinline__ int wave_incl_scan(int v, int lane)
{
#pragma unroll
    for (int off = 1; off < 64; off <<= 1) {
        int t = __shfl_up(v, off);
        if (lane >= off) v += t;
    }
    return v;
}

// ---------------------------------------------------------------------------
// Phase-1 aggregation for one node per 16-lane group (R8-verified form).
// No-max softmax: p = exp(a)/sum(exp(a)); alpha is O(1) so no overflow risk.
// ---------------------------------------------------------------------------
__device__ __forceinline__ void group_aggregate(
    const ushort4* __restrict__ hx, const int* __restrict__ col,
    const float* __restrict__ sarr, float adi, int beg, int deg, int fl,
    uint2* __restrict__ cw, float4& acc, float& s)
{
    s = 0.f;
    acc = float4{0.f, 0.f, 0.f, 0.f};

#define GATH(P) { float wv = __uint_as_float((P).y);                          \
                  ushort4 uu = hx[(P).x * 16 + fl];                           \
                  acc.x += wv * bf2f(uu.x); acc.y += wv * bf2f(uu.y);         \
                  acc.z += wv * bf2f(uu.z); acc.w += wv * bf2f(uu.w); }

    if (deg <= CAP) {
        // ---- register path: up to 4 edges/lane, statically indexed ----
        int c0 = 0, c1 = 0, c2 = 0, c3 = 0;
        float w0 = 0.f, w1 = 0.f, w2 = 0.f, w3 = 0.f;
        if (fl < deg)      { c0 = col[beg + fl];      float a = sarr[c0] + adi; a = a > 0.f ? a : NEG_SLOPE * a; w0 = __expf(a); }
        if (fl + 16 < deg) { c1 = col[beg + fl + 16]; float a = sarr[c1] + adi; a = a > 0.f ? a : NEG_SLOPE * a; w1 = __expf(a); }
        if (fl + 32 < deg) { c2 = col[beg + fl + 32]; float a = sarr[c2] + adi; a = a > 0.f ? a : NEG_SLOPE * a; w2 = __expf(a); }
        if (fl + 48 < deg) { c3 = col[beg + fl + 48]; float a = sarr[c3] + adi; a = a > 0.f ? a : NEG_SLOPE * a; w3 = __expf(a); }
        s = (w0 + w1) + (w2 + w3);

        // stash {col, weight}; zero-padding to degR via pre-zeroed c/w regs
        int degR = (deg + 7) & ~7;
        if (fl < degR)      { uint2 e; e.x = (unsigned)c0; e.y = __float_as_uint(w0); cw[fl] = e; }
        if (fl + 16 < degR) { uint2 e; e.x = (unsigned)c1; e.y = __float_as_uint(w1); cw[fl + 16] = e; }
        if (fl + 32 < degR) { uint2 e; e.x = (unsigned)c2; e.y = __float_as_uint(w2); cw[fl + 32] = e; }
        if (fl + 48 < degR) { uint2 e; e.x = (unsigned)c3; e.y = __float_as_uint(w3); cw[fl + 48] = e; }

        // gather: broadcast LDS reads, 8-deep global-load pipeline
        for (int i = 0; i < degR; i += 8) {
            uint2 p0 = cw[i],     p1 = cw[i + 1], p2 = cw[i + 2], p3 = cw[i + 3];
            uint2 p4 = cw[i + 4], p5 = cw[i + 5], p6 = cw[i + 6], p7 = cw[i + 7];
            GATH(p0); GATH(p1); GATH(p2); GATH(p3);
            GATH(p4); GATH(p5); GATH(p6); GATH(p7);
        }
    } else {
        // ---- rare fallback: 16-edge LDS chunks, no-max, single pass ----
        for (int base = 0; base < deg; base += 16) {
            int i = base + fl;
            uint2 e; e.x = 0u; e.y = 0u;
            if (i < deg) {
                int c = col[beg + i];
                float a = sarr[c] + adi;
                a = a > 0.f ? a : NEG_SLOPE * a;
                float wv = __expf(a);
                e.x = (unsigned)c; e.y = __float_as_uint(wv);
                s += wv;
            }
            cw[fl] = e;
            // wave-synchronous: same-wave LDS write->read needs no barrier
#pragma unroll
            for (int j = 0; j < 16; j += 8) {
                uint2 p0 = cw[j],     p1 = cw[j + 1], p2 = cw[j + 2], p3 = cw[j + 3];
                uint2 p4 = cw[j + 4], p5 = cw[j + 5], p6 = cw[j + 6], p7 = cw[j + 7];
                GATH(p0); GATH(p1); GATH(p2); GATH(p3);
                GATH(p4); GATH(p5); GATH(p6); GATH(p7);
            }
        }
    }
    // group reduction of the denominator — after gathers so it overlaps them
#pragma unroll
    for (int off = 8; off; off >>= 1) s += __shfl_xor(s, off);
#undef GATH
}

// ---------------------------------------------------------------------------
// Role: count + atomic region reservation + scatter for one edge chunk.
// ---------------------------------------------------------------------------
__device__ __forceinline__ void scatter_role(
    int k, const int4* __restrict__ dst4, const int4* __restrict__ src4,
    const int* __restrict__ dst, const int* __restrict__ src,
    int* __restrict__ gcur, int* __restrict__ ebuf,
    int NB, int E4, int E, int C4, char* smem)
{
    int tid = threadIdx.x;
    int* lh   = (int*)smem;
    int* lcur = lh + NBMAX;
    for (int i = tid; i < NB; i += 512) lh[i] = 0;
    __syncthreads();
    int i0 = k * C4, i1 = min(i0 + C4, E4);
    for (int i = i0 + tid; i < i1; i += 512) {
        int4 d = dst4[i];
        atomicAdd(&lh[d.x >> BSH], 1);
        atomicAdd(&lh[d.y >> BSH], 1);
        atomicAdd(&lh[d.z >> BSH], 1);
        atomicAdd(&lh[d.w >> BSH], 1);
    }
    if (k == NBLK - 1) {
        for (int e = E4 * 4 + tid; e < E; e += 512)
            atomicAdd(&lh[dst[e] >> BSH], 1);
    }
    __syncthreads();
    for (int b = tid; b < NB; b += 512) {
        int c = lh[b];
        lcur[b] = b * CAPB + (c ? atomicAdd(&gcur[b], c) : 0);
    }
    __syncthreads();
    for (int i = i0 + tid; i < i1; i += 512) {
        int4 d = dst4[i];
        int4 s = src4[i];
        int b, p;
        b = d.x >> BSH; p = atomicAdd(&lcur[b], 1);
        if (p < b * CAPB + CAPB) ebuf[p] = ((d.x & (BN - 1)) << 24) | s.x;
        b = d.y >> BSH; p = atomicAdd(&lcur[b], 1);
        if (p < b * CAPB + CAPB) ebuf[p] = ((d.y & (BN - 1)) << 24) | s.y;
        b = d.z >> BSH; p = atomicAdd(&lcur[b], 1);
        if (p < b * CAPB + CAPB) ebuf[p] = ((d.z & (BN - 1)) << 24) | s.z;
        b = d.w >> BSH; p = atomicAdd(&lcur[b], 1);
        if (p < b * CAPB + CAPB) ebuf[p] = ((d.w & (BN - 1)) << 24) | s.w;
    }
    if (k == NBLK - 1) {
        for (int e = E4 * 4 + tid; e < E; e += 512) {
            int d = dst[e];
            int b = d >> BSH;
            int p = atomicAdd(&lcur[b], 1);
            if (p < b * CAPB + CAPB)
                ebuf[p] = ((d & (BN - 1)) << 24) | src[e];
        }
    }
    __syncthreads();   // LDS safe for next unit
}

// ---------------------------------------------------------------------------
// Role: 64-node tile of {h = relu(x@W0+b0); hx = h@W1 (bf16); s/d arrays}.
// ---------------------------------------------------------------------------
__device__ __forceinline__ void mm_role(
    int tileIdx, const float* __restrict__ x, const float* __restrict__ W0,
    const float* __restrict__ b0, const float* __restrict__ W1,
    const float* __restrict__ a_src, const float* __restrict__ a_dst,
    float* __restrict__ h, ushort4* __restrict__ hxb4,
    float* __restrict__ sarr, float* __restrict__ darr, int n, char* smem)
{
    int tid = threadIdx.x;
    float* Wsh = (float*)smem;
    float* Hsh = Wsh + DD * DD;
    int fg = tid & 15, ng = tid >> 4;
    int tile0 = tileIdx * 64;

    for (int i = tid * 4; i < DD * DD; i += 2048)
        *(float4*)&Wsh[i] = *(const float4*)&W0[i];
    for (int p = 0; p < 2; ++p) {
        int nl = p * 32 + ng, gn = tile0 + nl;
        if (gn < n)
            *(float4*)&Hsh[nl * HS + 4 * fg] = *(const float4*)&x[gn * DD + 4 * fg];
    }
    __syncthreads();

    float4 acc[2];
#pragma unroll
    for (int j = 0; j < 2; ++j) acc[j] = float4{0.f, 0.f, 0.f, 0.f};
#pragma unroll 8
    for (int k = 0; k < DD; ++k) {
        float4 w4 = *(float4*)&Wsh[k * DD + 4 * fg];
#pragma unroll
        for (int j = 0; j < 2; ++j) {
            float hv = Hsh[(2 * ng + j) * HS + k];
            acc[j].x += hv * w4.x; acc[j].y += hv * w4.y;
            acc[j].z += hv * w4.z; acc[j].w += hv * w4.w;
        }
    }

    float4 b4 = *(const float4*)&b0[4 * fg];
    float4 o[2];
#pragma unroll
    for (int j = 0; j < 2; ++j) {
        o[j].x = fmaxf(acc[j].x + b4.x, 0.f);
        o[j].y = fmaxf(acc[j].y + b4.y, 0.f);
        o[j].z = fmaxf(acc[j].z + b4.z, 0.f);
        o[j].w = fmaxf(acc[j].w + b4.w, 0.f);
        int gn = tile0 + 2 * ng + j;
        if (gn < n) *(float4*)&h[gn * DD + 4 * fg] = o[j];
    }
    __syncthreads();

#pragma unroll
    for (int j = 0; j < 2; ++j)
        *(float4*)&Hsh[(2 * ng + j) * HS + 4 * fg] = o[j];
    for (int i = tid * 4; i < DD * DD; i += 2048)
        *(float4*)&Wsh[i] = *(const float4*)&W1[i];
    __syncthreads();

#pragma unroll
    for (int j = 0; j < 2; ++j) acc[j] = float4{0.f, 0.f, 0.f, 0.f};
#pragma unroll 8
    for (int k = 0; k < DD; ++k) {
        float4 w4 = *(float4*)&Wsh[k * DD + 4 * fg];
#pragma unroll
        for (int j = 0; j < 2; ++j) {
            float hv = Hsh[(2 * ng + j) * HS + k];
            acc[j].x += hv * w4.x; acc[j].y += hv * w4.y;
            acc[j].z += hv * w4.z; acc[j].w += hv * w4.w;
        }
    }

    float4 as4 = *(const float4*)&a_src[4 * fg];
    float4 ad4 = *(const float4*)&a_dst[4 * fg];
#pragma unroll
    for (int j = 0; j < 2; ++j) {
        int gn = tile0 + 2 * ng + j;
        if (gn < n) {
            ushort4 hb;
            hb.x = f2bf(acc[j].x); hb.y = f2bf(acc[j].y);
            hb.z = f2bf(acc[j].z); hb.w = f2bf(acc[j].w);
            hxb4[gn * 16 + fg] = hb;
        }
        float ps = acc[j].x * as4.x + acc[j].y * as4.y + acc[j].z * as4.z + acc[j].w * as4.w;
        float pd = acc[j].x * ad4.x + acc[j].y * ad4.y + acc[j].z * ad4.z + acc[j].w * ad4.w;
#pragma unroll
        for (int off = 8; off; off >>= 1) {
            ps += __shfl_xor(ps, off);
            pd += __shfl_xor(pd, off);
        }
        if (fg == 0 && gn < n) { sarr[gn] = ps; darr[gn] = pd; }
    }
    __syncthreads();   // LDS safe for next unit
}

// ---------------------------------------------------------------------------
// Role: per-bucket node ordering -> row_beg/degarr/col (R8 group_build body).
// ---------------------------------------------------------------------------
__device__ __forceinline__ void gb_role(
    int b, const int* __restrict__ ebuf, const int* __restrict__ gcur,
    int* __restrict__ row_beg, int* __restrict__ degarr,
    int* __restrict__ col, int N, char* smem)
{
    int tid = threadIdx.x;
    int* stage = (int*)smem;
    int* lcnt  = stage + STAGE_CAP;
    int* loff  = lcnt + BN;
    int* lcur  = loff + BN;
    int* wsum  = lcur + BN;
    int e0 = b * CAPB;
    int total = min(gcur[b], CAPB);
    int e1 = e0 + total;
    if (tid < BN) { lcnt[tid] = 0; lcur[tid] = 0; }
    __syncthreads();
    for (int e = e0 + tid; e < e1; e += 512)
        atomicAdd(&lcnt[((unsigned)ebuf[e]) >> 24], 1);
    __syncthreads();
    int lane = tid & 63, w = tid >> 6;
    int v = (tid < BN) ? lcnt[tid] : 0;
    int incl = wave_incl_scan(v, lane);
    if (tid < BN && lane == 63) wsum[w] = incl;
    __syncthreads();
    if (tid < BN) {
        int wo = 0;
        for (int i = 0; i < w; ++i) wo += wsum[i];
        int excl = wo + incl - v;
        loff[tid] = excl;
        int node = b * BN + tid;
        if (node < N) { row_beg[node] = e0 + excl; degarr[node] = v; }
    }
    __syncthreads();
    // total <= CAPB == STAGE_CAP: LDS-staged reorder, coalesced col write
    for (int e = e0 + tid; e < e1; e += 512) {
        int p = ebuf[e];
        int dl = ((unsigned)p) >> 24;
        int r = atomicAdd(&lcur[dl], 1);
        stage[loff[dl] + r] = p & 0xFFFFFF;
    }
    __syncthreads();
    for (int i = tid; i < total; i += 512)
        col[e0 + i] = stage[i];
    __syncthreads();   // LDS safe for next unit
}

// ---------------------------------------------------------------------------
// The single cooperative kernel: all 5 pipeline stages, grid.sync() between.
// ---------------------------------------------------------------------------
__global__ __launch_bounds__(512, 8) void fused_all(
    const int4* dst4, const int4* src4, const int* dst, const int* src,
    int* gcur, int* ebuf, int NB, int E4, int E, int C4,
    const float* x, const float* W0, const float* b0, const float* W1,
    const float* as1, const float* ad1, const float* b1,
    const float* W2, const float* as2, const float* ad2, const float* b2,
    float* h, ushort4* hxA, float* sA, float* dA,
    ushort4* hxB, float* sB, float* dB,
    int* row_beg, int* degarr, int* col,
    int n, int tiles, int ntiles)
{
    cg::grid_group grid = cg::this_grid();
    __shared__ __align__(16) char smem[SMEM_BYTES];
    int tid = threadIdx.x;
    int nb = gridDim.x;

    // ---- phase 0: zero bucket counters ----
    for (int i = blockIdx.x * 512 + tid; i < NB; i += nb * 512) gcur[i] = 0;
    grid.sync();

    // ---- phase 1: scatter (units 0..NBLK-1) || mm (units NBLK..) ----
    int U1 = NBLK + tiles;
    for (int u = blockIdx.x; u < U1; u += nb) {
        if (u < NBLK)
            scatter_role(u, dst4, src4, dst, src, gcur, ebuf, NB, E4, E, C4, smem);
        else
            mm_role(u - NBLK, x, W0, b0, W1, as1, ad1, h, hxA, sA, dA, n, smem);
    }
    grid.sync();

    // ---- phase 2: per-bucket CSR build ----
    for (int b = blockIdx.x; b < NB; b += nb)
        gb_role(b, ebuf, gcur, row_beg, degarr, col, n, smem);
    grid.sync();

    // ---- phase 3: layer-1 aggregate + layer-2 matmul ----
    {
        float* Wsh   = (float*)smem;                 // 16 KB
        uint2* cwbuf = (uint2*)(smem + DD * DD * 4); // 16.6 KB
        float* Hsh   = (float*)(smem + DD * DD * 4); // aliases cwbuf (8.7 KB)
        for (int i = tid * 4; i < DD * DD; i += 2048)
            *(float4*)&Wsh[i] = *(const float4*)&W2[i];
        __syncthreads();

        int w = tid >> 6, lane = tid & 63, grp = lane >> 4, fl = lane & 15;
        for (int t = blockIdx.x; t < ntiles; t += nb) {
            int tile0 = t * AMM_NODES;
            int nl = 4 * w + grp;
            int v = tile0 + nl;
            bool alive = v < n;

            int beg = 0, deg = 0;
            float adi = 0.f;
            if (alive) { beg = row_beg[v]; deg = degarr[v]; adi = dA[v]; }

            float4 acc; float s;
            group_aggregate(hxA, col, sA, adi, beg, deg, fl, &cwbuf[nl * CWS], acc, s);

            float4 resid = float4{0.f, 0.f, 0.f, 0.f};
            {
                float inv = (s > 0.f) ? 1.f / s : 0.f;
                float4 b4 = ((const float4*)b1)[fl];
                float4 o;
                o.x = fmaxf(acc.x * inv + b4.x, 0.f);
                o.y = fmaxf(acc.y * inv + b4.y, 0.f);
                o.z = fmaxf(acc.z * inv + b4.z, 0.f);
                o.w = fmaxf(acc.w * inv + b4.w, 0.f);
                if (alive) {
                    float4* hp = (float4*)&h[v * DD + 4 * fl];
                    float4 cur = *hp;
                    cur.x += o.x; cur.y += o.y; cur.z += o.z; cur.w += o.w;
                    *hp = cur;            // layer-1 output (residual base)
                    resid = cur;
                }
            }
            __syncthreads();              // all cw reads done
            *(float4*)&Hsh[nl * HS + 4 * fl] = resid;
            __syncthreads();

            // layer-2 matmul: 32 rows x 64 cols, 1 row/thread
            int nl2 = tid >> 4;
            int fg = tid & 15;
            float4 acc2 = float4{0.f, 0.f, 0.f, 0.f};
#pragma unroll 8
            for (int k = 0; k < DD; ++k) {
                float4 w4 = *(float4*)&Wsh[k * DD + 4 * fg];
                float hv = Hsh[nl2 * HS + k];
                acc2.x += hv * w4.x; acc2.y += hv * w4.y;
                acc2.z += hv * w4.z; acc2.w += hv * w4.w;
            }
            int gn = tile0 + nl2;
            float4 as4 = *(const float4*)&as2[4 * fg];
            float4 ad4 = *(const float4*)&ad2[4 * fg];
            if (gn < n) {
                ushort4 hb;
                hb.x = f2bf(acc2.x); hb.y = f2bf(acc2.y);
                hb.z = f2bf(acc2.z); hb.w = f2bf(acc2.w);
                hxB[gn * 16 + fg] = hb;
            }
            float ps = acc2.x * as4.x + acc2.y * as4.y + acc2.z * as4.z + acc2.w * as4.w;
            float pd = acc2.x * ad4.x + acc2.y * ad4.y + acc2.z * ad4.z + acc2.w * ad4.w;
#pragma unroll
            for (int off = 8; off; off >>= 1) {
                ps += __shfl_xor(ps, off);
                pd += __shfl_xor(pd, off);
            }
            if (fg == 0 && gn < n) { sB[gn] = ps; dB[gn] = pd; }
            __syncthreads();              // cw/Hsh free for next tile
        }
    }
    grid.sync();

    // ---- phase 4: final aggregate + relu + residual ----
    {
        uint2* cwbuf = (uint2*)smem;
        int w = tid >> 6, lane = tid & 63, grp = lane >> 4, fl = lane & 15;
        for (int t = blockIdx.x; t < ntiles; t += nb) {
            int nl = 4 * w + grp;
            int v = t * AMM_NODES + nl;
            bool alive = v < n;

            int beg = 0, deg = 0;
            float adi = 0.f;
            if (alive) { beg = row_beg[v]; deg = degarr[v]; adi = dB[v]; }

            float4 acc; float s;
            group_aggregate(hxB, col, sB, adi, beg, deg, fl, &cwbuf[nl * CWS], acc, s);

            if (alive) {
                float inv = (s > 0.f) ? 1.f / s : 0.f;
                float4 b4 = ((const float4*)b2)[fl];
                float4 o;
                o.x = fmaxf(acc.x * inv + b4.x, 0.f);
                o.y = fmaxf(acc.y * inv + b4.y, 0.f);
                o.z = fmaxf(acc.z * inv + b4.z, 0.f);
                o.w = fmaxf(acc.w * inv + b4.w, 0.f);
                float4* hp = (float4*)&h[v * DD + 4 * fl];
                float4 cur = *hp;
                cur.x += o.x; cur.y += o.y; cur.z += o.z; cur.w += o.w;
                *hp = cur;
            }
            // cw rows are per-group, same-wave read/write: no barrier needed
        }
    }
}

// ---------------------------------------------------------------------------
extern "C" void kernel_launch(void* const* d_in, const int* in_sizes, int n_in,
                              void* d_out, int out_size, void* d_ws, size_t ws_size,
                              hipStream_t stream)
{
    const float* x  = (const float*)d_in[0];
    const int*   ei = (const int*)d_in[1];
    const float* W0 = (const float*)d_in[4];
    const float* b0 = (const float*)d_in[5];
    const float* W1 = (const float*)d_in[6];
    const float* as1= (const float*)d_in[7];
    const float* ad1= (const float*)d_in[8];
    const float* b1 = (const float*)d_in[9];
    const float* W2 = (const float*)d_in[10];
    const float* as2= (const float*)d_in[11];
    const float* ad2= (const float*)d_in[12];
    const float* b2 = (const float*)d_in[13];

    int N = in_sizes[0] / DD;
    int E = in_sizes[1] / 2;
    int E4 = E >> 2;
    int C4 = (E4 + NBLK - 1) / NBLK;
    int NB = (N + BN - 1) >> BSH;
    float* h = (float*)d_out;

    // workspace layout
    ushort4* hxA  = (ushort4*)d_ws;                      // N*16 ushort4 (6.4 MB)
    ushort4* hxB  = hxA + (size_t)N * 16;                // N*16 ushort4 (6.4 MB)
    float* sA     = (float*)(hxB + (size_t)N * 16);      // N
    float* dA     = sA + N;                              // N
    float* sB     = dA + N;                              // N
    float* dB     = sB + N;                              // N
    int*   row_beg= (int*)(dB + N);                      // N
    int*   degarr = row_beg + N;                         // N
    int*   gcur   = degarr + N;                          // NB
    int*   ebuf   = gcur + NB;                           // NB*CAPB (~4.8 MB)
    int*   colb   = ebuf + (size_t)NB * CAPB;            // NB*CAPB (~4.8 MB)

    const int* src = ei;
    const int* dst = ei + E;
    const int4* dst4 = (const int4*)dst;
    const int4* src4 = (const int4*)src;

    int tiles  = (N + 63) / 64;
    int ntiles = (N + AMM_NODES - 1) / AMM_NODES;

    // grid sizing: co-residency capacity from the occupancy API (capture-time)
    int maxActive = 0;
    hipOccupancyMaxActiveBlocksPerMultiprocessor(&maxActive, fused_all, 512, 0);
    if (maxActive < 1) maxActive = 1;
    long capacity = (long)maxActive * 256;
    int grid = (int)(capacity < ntiles ? capacity : ntiles);
    if (grid < 1) grid = 1;

    void* args[] = {
        (void*)&dst4, (void*)&src4, (void*)&dst, (void*)&src,
        (void*)&gcur, (void*)&ebuf, (void*)&NB, (void*)&E4, (void*)&E, (void*)&C4,
        (void*)&x, (void*)&W0, (void*)&b0, (void*)&W1,
        (void*)&as1, (void*)&ad1, (void*)&b1,
        (void*)&W2, (void*)&as2, (void*)&ad2, (void*)&b2,
        (void*)&h, (void*)&hxA, (void*)&sA, (void*)&dA,
        (void*)&hxB, (void*)&sB, (void*)&dB,
        (void*)&row_beg, (void*)&degarr, (void*)&colb,
        (void*)&N, (void*)&tiles, (void*)&ntiles
    };
    hipLaunchCooperativeKernel(fused_all, dim3(grid), dim3(512), args, 0, stream);
}

// Round 11
// 177.891 us; speedup vs baseline: 2.4142x; 2.4142x over previous
//
#include <hip/hip_runtime.h>

#define DD 64
#define NEG_SLOPE 0.2f
#define HS 68          // padded LDS stride for h tile
#define CAP 64         // per-node register path capacity (deg~Pois(16))
#define BSH 8          // bucket = dst >> 8 (256 nodes per bucket)
#define BN  256        // nodes per bucket
#define NBMAX 256      // max buckets supported by LDS hists
#define NBLK 256       // edge-chunk blocks for the multi-split
#define CAPB 6144      // per-bucket region capacity (mean ~4082, >30 sigma)
#define STAGE_CAP 6144 // LDS col staging per bucket
#define AMM_NODES 32   // nodes per aggregation block (8 waves x 4 groups)
#define CWS 65         // cw row stride (uint2) — padded to break bank conflicts

// fp32 -> bf16 with round-to-nearest-even (finite inputs)
__device__ __forceinline__ unsigned short f2bf(float f)
{
    unsigned u = __float_as_uint(f);
    u += 0x7FFFu + ((u >> 16) & 1u);
    return (unsigned short)(u >> 16);
}
__device__ __forceinline__ float bf2f(unsigned short b)
{
    return __uint_as_float(((unsigned)b) << 16);
}

__device__ __forceinline__ int wave_incl_scan(int v, int lane)
{
#pragma unroll
    for (int off = 1; off < 64; off <<= 1) {
        int t = __shfl_up(v, off);
        if (lane >= off) v += t;
    }
    return v;
}

// ---------------------------------------------------------------------------
// Phase-1 aggregation for one node per 16-lane group (R4/R8-verified form).
// No-max softmax: p = exp(a)/sum(exp(a)); alpha is O(1) so no overflow risk.
// ---------------------------------------------------------------------------
__device__ __forceinline__ void group_aggregate(
    const ushort4* __restrict__ hx, const int* __restrict__ col,
    const float* __restrict__ sarr, float adi, int beg, int deg, int fl,
    uint2* __restrict__ cw, float4& acc, float& s)
{
    s = 0.f;
    acc = float4{0.f, 0.f, 0.f, 0.f};

#define GATH(P) { float wv = __uint_as_float((P).y);                          \
                  ushort4 uu = hx[(P).x * 16 + fl];                           \
                  acc.x += wv * bf2f(uu.x); acc.y += wv * bf2f(uu.y);         \
                  acc.z += wv * bf2f(uu.z); acc.w += wv * bf2f(uu.w); }

    if (deg <= CAP) {
        // ---- register path: up to 4 edges/lane, statically indexed ----
        int c0 = 0, c1 = 0, c2 = 0, c3 = 0;
        float w0 = 0.f, w1 = 0.f, w2 = 0.f, w3 = 0.f;
        if (fl < deg)      { c0 = col[beg + fl];      float a = sarr[c0] + adi; a = a > 0.f ? a : NEG_SLOPE * a; w0 = __expf(a); }
        if (fl + 16 < deg) { c1 = col[beg + fl + 16]; float a = sarr[c1] + adi; a = a > 0.f ? a : NEG_SLOPE * a; w1 = __expf(a); }
        if (fl + 32 < deg) { c2 = col[beg + fl + 32]; float a = sarr[c2] + adi; a = a > 0.f ? a : NEG_SLOPE * a; w2 = __expf(a); }
        if (fl + 48 < deg) { c3 = col[beg + fl + 48]; float a = sarr[c3] + adi; a = a > 0.f ? a : NEG_SLOPE * a; w3 = __expf(a); }
        s = (w0 + w1) + (w2 + w3);

        // stash {col, weight}; zero-padding to degR via pre-zeroed c/w regs
        int degR = (deg + 7) & ~7;
        if (fl < degR)      { uint2 e; e.x = (unsigned)c0; e.y = __float_as_uint(w0); cw[fl] = e; }
        if (fl + 16 < degR) { uint2 e; e.x = (unsigned)c1; e.y = __float_as_uint(w1); cw[fl + 16] = e; }
        if (fl + 32 < degR) { uint2 e; e.x = (unsigned)c2; e.y = __float_as_uint(w2); cw[fl + 32] = e; }
        if (fl + 48 < degR) { uint2 e; e.x = (unsigned)c3; e.y = __float_as_uint(w3); cw[fl + 48] = e; }

        // gather: broadcast LDS reads, 8-deep global-load pipeline
        for (int i = 0; i < degR; i += 8) {
            uint2 p0 = cw[i],     p1 = cw[i + 1], p2 = cw[i + 2], p3 = cw[i + 3];
            uint2 p4 = cw[i + 4], p5 = cw[i + 5], p6 = cw[i + 6], p7 = cw[i + 7];
            GATH(p0); GATH(p1); GATH(p2); GATH(p3);
            GATH(p4); GATH(p5); GATH(p6); GATH(p7);
        }
    } else {
        // ---- rare fallback: 16-edge LDS chunks, no-max, single pass ----
        for (int base = 0; base < deg; base += 16) {
            int i = base + fl;
            uint2 e; e.x = 0u; e.y = 0u;
            if (i < deg) {
                int c = col[beg + i];
                float a = sarr[c] + adi;
                a = a > 0.f ? a : NEG_SLOPE * a;
                float wv = __expf(a);
                e.x = (unsigned)c; e.y = __float_as_uint(wv);
                s += wv;
            }
            cw[fl] = e;
            // wave-synchronous: same-wave LDS write->read needs no barrier
#pragma unroll
            for (int j = 0; j < 16; j += 8) {
                uint2 p0 = cw[j],     p1 = cw[j + 1], p2 = cw[j + 2], p3 = cw[j + 3];
                uint2 p4 = cw[j + 4], p5 = cw[j + 5], p6 = cw[j + 6], p7 = cw[j + 7];
                GATH(p0); GATH(p1); GATH(p2); GATH(p3);
                GATH(p4); GATH(p5); GATH(p6); GATH(p7);
            }
        }
    }
    // group reduction of the denominator — after gathers so it overlaps them
#pragma unroll
    for (int off = 8; off; off >>= 1) s += __shfl_xor(s, off);
#undef GATH
}

// ---------------------------------------------------------------------------
// K1: grid-partition fusion (R8-verified). Blocks [0,NBLK): count+reserve+
// scatter. Blocks [NBLK, NBLK+tiles): mm (layer0 + GAT1). gcur pre-zeroed.
// ---------------------------------------------------------------------------
__global__ __launch_bounds__(512) void scatter_mm(
    const int4* __restrict__ dst4, const int4* __restrict__ src4,
    const int* __restrict__ dst, const int* __restrict__ src,
    int* __restrict__ gcur, int* __restrict__ ebuf,
    int NB, int E4, int E, int C4,
    const float* __restrict__ x, const float* __restrict__ W0,
    const float* __restrict__ b0, const float* __restrict__ W1,
    const float* __restrict__ a_src, const float* __restrict__ a_dst,
    float* __restrict__ h, ushort4* __restrict__ hxb4,
    float* __restrict__ sarr, float* __restrict__ darr, int n)
{
    __shared__ float smem[DD * DD + DD * HS];   // 33.8 KB, shared by both roles
    int tid = threadIdx.x;

    if (blockIdx.x < NBLK) {
        int* lh   = (int*)smem;
        int* lcur = lh + NBMAX;
        int k = blockIdx.x;
        for (int i = tid; i < NB; i += 512) lh[i] = 0;
        __syncthreads();
        int i0 = k * C4, i1 = min(i0 + C4, E4);
        for (int i = i0 + tid; i < i1; i += 512) {
            int4 d = dst4[i];
            atomicAdd(&lh[d.x >> BSH], 1);
            atomicAdd(&lh[d.y >> BSH], 1);
            atomicAdd(&lh[d.z >> BSH], 1);
            atomicAdd(&lh[d.w >> BSH], 1);
        }
        if (k == NBLK - 1) {
            for (int e = E4 * 4 + tid; e < E; e += 512)
                atomicAdd(&lh[dst[e] >> BSH], 1);
        }
        __syncthreads();
        for (int b = tid; b < NB; b += 512) {
            int c = lh[b];
            lcur[b] = b * CAPB + (c ? atomicAdd(&gcur[b], c) : 0);
        }
        __syncthreads();
        for (int i = i0 + tid; i < i1; i += 512) {
            int4 d = dst4[i];
            int4 s = src4[i];
            int b, p;
            b = d.x >> BSH; p = atomicAdd(&lcur[b], 1);
            if (p < b * CAPB + CAPB) ebuf[p] = ((d.x & (BN - 1)) << 24) | s.x;
            b = d.y >> BSH; p = atomicAdd(&lcur[b], 1);
            if (p < b * CAPB + CAPB) ebuf[p] = ((d.y & (BN - 1)) << 24) | s.y;
            b = d.z >> BSH; p = atomicAdd(&lcur[b], 1);
            if (p < b * CAPB + CAPB) ebuf[p] = ((d.z & (BN - 1)) << 24) | s.z;
            b = d.w >> BSH; p = atomicAdd(&lcur[b], 1);
            if (p < b * CAPB + CAPB) ebuf[p] = ((d.w & (BN - 1)) << 24) | s.w;
        }
        if (k == NBLK - 1) {
            for (int e = E4 * 4 + tid; e < E; e += 512) {
                int d = dst[e];
                int b = d >> BSH;
                int p = atomicAdd(&lcur[b], 1);
                if (p < b * CAPB + CAPB)
                    ebuf[p] = ((d & (BN - 1)) << 24) | src[e];
            }
        }
        return;
    }

    // ---- mm role ----
    float* Wsh = smem;
    float* Hsh = smem + DD * DD;
    int fg = tid & 15, ng = tid >> 4;
    int tile0 = (blockIdx.x - NBLK) * 64;

    for (int i = tid * 4; i < DD * DD; i += 2048)
        *(float4*)&Wsh[i] = *(const float4*)&W0[i];
    for (int p = 0; p < 2; ++p) {
        int nl = p * 32 + ng, gn = tile0 + nl;
        if (gn < n)
            *(float4*)&Hsh[nl * HS + 4 * fg] = *(const float4*)&x[gn * DD + 4 * fg];
    }
    __syncthreads();

    float4 acc[2];
#pragma unroll
    for (int j = 0; j < 2; ++j) acc[j] = float4{0.f, 0.f, 0.f, 0.f};
#pragma unroll 8
    for (int k = 0; k < DD; ++k) {
        float4 w4 = *(float4*)&Wsh[k * DD + 4 * fg];
#pragma unroll
        for (int j = 0; j < 2; ++j) {
            float hv = Hsh[(2 * ng + j) * HS + k];
            acc[j].x += hv * w4.x; acc[j].y += hv * w4.y;
            acc[j].z += hv * w4.z; acc[j].w += hv * w4.w;
        }
    }

    float4 b4 = *(const float4*)&b0[4 * fg];
    float4 o[2];
#pragma unroll
    for (int j = 0; j < 2; ++j) {
        o[j].x = fmaxf(acc[j].x + b4.x, 0.f);
        o[j].y = fmaxf(acc[j].y + b4.y, 0.f);
        o[j].z = fmaxf(acc[j].z + b4.z, 0.f);
        o[j].w = fmaxf(acc[j].w + b4.w, 0.f);
        int gn = tile0 + 2 * ng + j;
        if (gn < n) *(float4*)&h[gn * DD + 4 * fg] = o[j];
    }
    __syncthreads();

#pragma unroll
    for (int j = 0; j < 2; ++j)
        *(float4*)&Hsh[(2 * ng + j) * HS + 4 * fg] = o[j];
    for (int i = tid * 4; i < DD * DD; i += 2048)
        *(float4*)&Wsh[i] = *(const float4*)&W1[i];
    __syncthreads();

#pragma unroll
    for (int j = 0; j < 2; ++j) acc[j] = float4{0.f, 0.f, 0.f, 0.f};
#pragma unroll 8
    for (int k = 0; k < DD; ++k) {
        float4 w4 = *(float4*)&Wsh[k * DD + 4 * fg];
#pragma unroll
        for (int j = 0; j < 2; ++j) {
            float hv = Hsh[(2 * ng + j) * HS + k];
            acc[j].x += hv * w4.x; acc[j].y += hv * w4.y;
            acc[j].z += hv * w4.z; acc[j].w += hv * w4.w;
        }
    }

    float4 as4 = *(const float4*)&a_src[4 * fg];
    float4 ad4 = *(const float4*)&a_dst[4 * fg];
#pragma unroll
    for (int j = 0; j < 2; ++j) {
        int gn = tile0 + 2 * ng + j;
        if (gn < n) {
            ushort4 hb;
            hb.x = f2bf(acc[j].x); hb.y = f2bf(acc[j].y);
            hb.z = f2bf(acc[j].z); hb.w = f2bf(acc[j].w);
            hxb4[gn * 16 + fg] = hb;
        }
        float ps = acc[j].x * as4.x + acc[j].y * as4.y + acc[j].z * as4.z + acc[j].w * as4.w;
        float pd = acc[j].x * ad4.x + acc[j].y * ad4.y + acc[j].z * ad4.z + acc[j].w * ad4.w;
#pragma unroll
        for (int off = 8; off; off >>= 1) {
            ps += __shfl_xor(ps, off);
            pd += __shfl_xor(pd, off);
        }
        if (fg == 0 && gn < n) { sarr[gn] = ps; darr[gn] = pd; }
    }
}

// ---------------------------------------------------------------------------
// K2: per-bucket node ordering -> row_beg/degarr/col (padded bucket regions)
// ---------------------------------------------------------------------------
__global__ __launch_bounds__(512) void group_build(
    const int* __restrict__ ebuf, const int* __restrict__ gcur,
    int* __restrict__ row_beg, int* __restrict__ degarr,
    int* __restrict__ col, int N)
{
    __shared__ int lcnt[BN];
    __shared__ int loff[BN];
    __shared__ int lcur[BN];
    __shared__ int wsum[4];
    __shared__ int stage[STAGE_CAP];
    int b = blockIdx.x, tid = threadIdx.x;
    int e0 = b * CAPB;
    int total = min(gcur[b], CAPB);
    int e1 = e0 + total;
    if (tid < BN) { lcnt[tid] = 0; lcur[tid] = 0; }
    __syncthreads();
    for (int e = e0 + tid; e < e1; e += 512)
        atomicAdd(&lcnt[((unsigned)ebuf[e]) >> 24], 1);
    __syncthreads();
    int lane = tid & 63, w = tid >> 6;
    int v = (tid < BN) ? lcnt[tid] : 0;
    int incl = wave_incl_scan(v, lane);
    if (tid < BN && lane == 63) wsum[w] = incl;
    __syncthreads();
    if (tid < BN) {
        int wo = 0;
        for (int i = 0; i < w; ++i) wo += wsum[i];
        int excl = wo + incl - v;
        loff[tid] = excl;
        int node = b * BN + tid;
        if (node < N) { row_beg[node] = e0 + excl; degarr[node] = v; }
    }
    __syncthreads();
    // total <= CAPB == STAGE_CAP always: LDS-staged reorder, coalesced col write
    for (int e = e0 + tid; e < e1; e += 512) {
        int p = ebuf[e];
        int dl = ((unsigned)p) >> 24;
        int r = atomicAdd(&lcur[dl], 1);
        stage[loff[dl] + r] = p & 0xFFFFFF;
    }
    __syncthreads();
    for (int i = tid; i < total; i += 512)
        col[e0 + i] = stage[i];
}

// ---------------------------------------------------------------------------
// K3: fused layer-1 aggregate + layer-2 matmul. 32 nodes/block, 16 lanes/node.
// cw LDS table aliased with Hsh (dead after phase 1; residual kept in regs).
// ---------------------------------------------------------------------------
__global__ __launch_bounds__(512) void agg_mm(
    const ushort4* __restrict__ hxA, const int* __restrict__ row_beg,
    const int* __restrict__ degarr, const int* __restrict__ col,
    const float* __restrict__ sA, const float* __restrict__ dA,
    const float* __restrict__ bias,
    float* __restrict__ h, const float* __restrict__ W,
    const float* __restrict__ a_src, const float* __restrict__ a_dst,
    ushort4* __restrict__ hxB, float* __restrict__ sB, float* __restrict__ dB,
    int n)
{
    __shared__ float Wsh[DD * DD];
    __shared__ uint2 cwbuf[AMM_NODES][CWS];   // 16.6 KB; aliased as Hsh below
    float* Hsh = (float*)&cwbuf[0][0];        // AMM_NODES*HS*4 = 8.7 KB fits

    int tid = threadIdx.x;
    int w = tid >> 6, lane = tid & 63, grp = lane >> 4, fl = lane & 15;
    int nl = 4 * w + grp;                     // node-local 0..31
    int tile0 = blockIdx.x * AMM_NODES;
    int v = tile0 + nl;
    bool alive = v < n;

    // stage W2 early (separate LDS, visibility via the barrier below)
    for (int i = tid * 4; i < DD * DD; i += 2048)
        *(float4*)&Wsh[i] = *(const float4*)&W[i];

    int beg = 0, deg = 0;
    float adi = 0.f;
    if (alive) {
        beg = row_beg[v];
        deg = degarr[v];
        adi = dA[v];
    }

    float4 acc; float s;
    group_aggregate(hxA, col, sA, adi, beg, deg, fl, &cwbuf[nl][0], acc, s);

    float4 resid = float4{0.f, 0.f, 0.f, 0.f};
    {
        float inv = (s > 0.f) ? 1.f / s : 0.f;
        float4 b4 = ((const float4*)bias)[fl];
        float4 o;
        o.x = fmaxf(acc.x * inv + b4.x, 0.f);
        o.y = fmaxf(acc.y * inv + b4.y, 0.f);
        o.z = fmaxf(acc.z * inv + b4.z, 0.f);
        o.w = fmaxf(acc.w * inv + b4.w, 0.f);
        if (alive) {
            float4* hp = (float4*)&h[v * DD + 4 * fl];
            float4 cur = *hp;
            cur.x += o.x; cur.y += o.y; cur.z += o.z; cur.w += o.w;
            *hp = cur;            // layer-1 output (residual base)
            resid = cur;
        }
    }
    __syncthreads();              // all cw reads done; Wsh staged
    *(float4*)&Hsh[nl * HS + 4 * fl] = resid;
    __syncthreads();

    // ---- layer-2 matmul: 32 rows x 64 cols, 1 row/thread ----
    int nl2 = tid >> 4;                                 // 0..31
    int fg = tid & 15;
    float4 acc2 = float4{0.f, 0.f, 0.f, 0.f};
#pragma unroll 8
    for (int k = 0; k < DD; ++k) {
        float4 w4 = *(float4*)&Wsh[k * DD + 4 * fg];
        float hv = Hsh[nl2 * HS + k];
        acc2.x += hv * w4.x; acc2.y += hv * w4.y;
        acc2.z += hv * w4.z; acc2.w += hv * w4.w;
    }
    int gn = tile0 + nl2;
    float4 as4 = *(const float4*)&a_src[4 * fg];
    float4 ad4 = *(const float4*)&a_dst[4 * fg];
    if (gn < n) {
        ushort4 hb;
        hb.x = f2bf(acc2.x); hb.y = f2bf(acc2.y);
        hb.z = f2bf(acc2.z); hb.w = f2bf(acc2.w);
        hxB[gn * 16 + fg] = hb;
    }
    float ps = acc2.x * as4.x + acc2.y * as4.y + acc2.z * as4.z + acc2.w * as4.w;
    float pd = acc2.x * ad4.x + acc2.y * ad4.y + acc2.z * ad4.z + acc2.w * ad4.w;
#pragma unroll
    for (int off = 8; off; off >>= 1) {
        ps += __shfl_xor(ps, off);
        pd += __shfl_xor(pd, off);
    }
    if (fg == 0 && gn < n) { sB[gn] = ps; dB[gn] = pd; }
}

// ---------------------------------------------------------------------------
// K4: final softmax aggregation + relu + residual. 32 nodes/block.
// ---------------------------------------------------------------------------
__global__ __launch_bounds__(512) void aggregate(
    const ushort4* __restrict__ hxb4, const int* __restrict__ row_beg,
    const int* __restrict__ degarr, const int* __restrict__ col,
    const float* __restrict__ sarr, const float* __restrict__ darr,
    const float* __restrict__ bias, float* __restrict__ h, int n)
{
    __shared__ uint2 cwbuf[AMM_NODES][CWS];   // 16.6 KB
    int tid = threadIdx.x;
    int w = tid >> 6, lane = tid & 63, grp = lane >> 4, fl = lane & 15;
    int nl = 4 * w + grp;
    int v = blockIdx.x * AMM_NODES + nl;
    bool alive = v < n;

    int beg = 0, deg = 0;
    float adi = 0.f;
    if (alive) {
        beg = row_beg[v];
        deg = degarr[v];
        adi = darr[v];
    }

    float4 acc; float s;
    group_aggregate(hxb4, col, sarr, adi, beg, deg, fl, &cwbuf[nl][0], acc, s);

    if (alive) {
        float inv = (s > 0.f) ? 1.f / s : 0.f;
        float4 b4 = ((const float4*)bias)[fl];
        float4 o;
        o.x = fmaxf(acc.x * inv + b4.x, 0.f);
        o.y = fmaxf(acc.y * inv + b4.y, 0.f);
        o.z = fmaxf(acc.z * inv + b4.z, 0.f);
        o.w = fmaxf(acc.w * inv + b4.w, 0.f);
        float4* hp = (float4*)&h[v * DD + 4 * fl];
        float4 cur = *hp;
        cur.x += o.x; cur.y += o.y; cur.z += o.z; cur.w += o.w;
        *hp = cur;
    }
}

// ---------------------------------------------------------------------------
extern "C" void kernel_launch(void* const* d_in, const int* in_sizes, int n_in,
                              void* d_out, int out_size, void* d_ws, size_t ws_size,
                              hipStream_t stream)
{
    const float* x  = (const float*)d_in[0];
    const int*   ei = (const int*)d_in[1];
    const float* W0 = (const float*)d_in[4];
    const float* b0 = (const float*)d_in[5];
    const float* W1 = (const float*)d_in[6];
    const float* as1= (const float*)d_in[7];
    const float* ad1= (const float*)d_in[8];
    const float* b1 = (const float*)d_in[9];
    const float* W2 = (const float*)d_in[10];
    const float* as2= (const float*)d_in[11];
    const float* ad2= (const float*)d_in[12];
    const float* b2 = (const float*)d_in[13];

    int N = in_sizes[0] / DD;
    int E = in_sizes[1] / 2;
    int E4 = E >> 2;
    int C4 = (E4 + NBLK - 1) / NBLK;
    int NB = (N + BN - 1) >> BSH;
    float* h = (float*)d_out;

    // workspace layout
    ushort4* hxA  = (ushort4*)d_ws;                      // N*16 ushort4 (6.4 MB)
    ushort4* hxB  = hxA + (size_t)N * 16;                // N*16 ushort4 (6.4 MB)
    float* sA     = (float*)(hxB + (size_t)N * 16);      // N
    float* dA     = sA + N;                              // N
    float* sB     = dA + N;                              // N
    float* dB     = sB + N;                              // N
    int*   row_beg= (int*)(dB + N);                      // N
    int*   degarr = row_beg + N;                         // N
    int*   gcur   = degarr + N;                          // NB
    int*   ebuf   = gcur + NB;                           // NB*CAPB (~4.8 MB)
    int*   colb   = ebuf + (size_t)NB * CAPB;            // NB*CAPB (~4.8 MB)

    const int* src = ei;
    const int* dst = ei + E;
    const int4* dst4 = (const int4*)dst;
    const int4* src4 = (const int4*)src;

    int tiles   = (N + 63) / 64;
    int ntiles  = (N + AMM_NODES - 1) / AMM_NODES;

    // K0: zero bucket counters (graph-capturable async memset)
    hipMemsetAsync(gcur, 0, NB * sizeof(int), stream);
    // K1: scatter co-dispatched with layer0+GAT1 matmul
    scatter_mm<<<NBLK + tiles, 512, 0, stream>>>(
        dst4, src4, dst, src, gcur, ebuf, NB, E4, E, C4,
        x, W0, b0, W1, as1, ad1, h, hxA, sA, dA, N);
    // K2: per-bucket ordering -> row_beg/degarr/col
    group_build<<<NB, 512, 0, stream>>>(ebuf, gcur, row_beg, degarr, colb, N);
    // K3: layer-1 aggregate fused with layer-2 matmul
    agg_mm<<<ntiles, 512, 0, stream>>>(hxA, row_beg, degarr, colb, sA, dA, b1,
                                       h, W2, as2, ad2, hxB, sB, dB, N);
    // K4: final aggregate + residual
    aggregate<<<ntiles, 512, 0, stream>>>(hxB, row_beg, degarr, colb,
                                          sB, dB, b2, h, N);
}